// Round 14
// baseline (173.161 us; speedup 1.0000x reference)
//
#include <hip/hip_runtime.h>

#define HW 64
#define CIN 256
#define OC1 128
#define NJ 49
#define KZ 8                 // K-split: each conv1 block does 32 ic x 49 taps

typedef short bf16x8 __attribute__((ext_vector_type(8)));
typedef float f32x4 __attribute__((ext_vector_type(4)));

__device__ __forceinline__ unsigned f2bf_pack(float a, float b) {
    unsigned ua = __float_as_uint(a);
    ua += 0x7FFF + ((ua >> 16) & 1);
    unsigned ub = __float_as_uint(b);
    ub += 0x7FFF + ((ub >> 16) & 1);
    return (ua >> 16) | (ub & 0xFFFF0000u);
}

__device__ __forceinline__ unsigned short f2bf(float a) {
    unsigned u = __float_as_uint(a);
    u += 0x7FFF + ((u >> 16) & 1);
    return (unsigned short)(u >> 16);
}

// ---------------------------------------------------------------------------
// prep: merged wtrans + xtrans (one launch, tails overlap).   (r13 verbatim)
// blocks 0..255:   w1 fp32 [128][256][49] -> w1t bf16 [kz8][tap49][oc128][ic32]
// blocks 256..863: x fp32 [b][256][64][64] -> xbf bf16 [b][76pr][80col][256ic]
// ---------------------------------------------------------------------------
__global__ __launch_bounds__(256) void prep_kernel(
    const float* __restrict__ w1, unsigned short* __restrict__ w1t,
    const float* __restrict__ x, unsigned short* __restrict__ xbf)
{
    __shared__ __align__(16) char smraw[25088];
    const int t = threadIdx.x;

    if (blockIdx.x < 256) {
        // ---- wtrans ----
        float* ws = (float*)smraw;            // [ic-local 128][tap 49]
        const int oc = blockIdx.x >> 1, ih = blockIdx.x & 1;
        const float4* src = (const float4*)(w1 + ((size_t)oc * 256 + ih * 128) * 49);
        for (int f = t; f < 1568; f += 256)
            ((float4*)ws)[f] = src[f];
        __syncthreads();
        for (int f = t; f < 4 * 49 * 32; f += 256) {
            const int icl = f & 31, r = f >> 5;          // r = kzl*49 + tap
            const int kzl = r / 49, tap = r - kzl * 49;
            // LDS read stride 49 words (odd) -> conflict-free
            w1t[(((size_t)(ih * 4 + kzl) * 49 + tap) * 128 + oc) * 32 + icl] =
                f2bf(ws[(kzl * 32 + icl) * 49 + tap]);
        }
        return;
    }

    // ---- xtrans ----
    uint2* lsq = (uint2*)smraw;               // [w][c4], c4 XOR-swizzled by w
    const int idx = blockIdx.x - 256;         // 608 = 76 * 8
    const int pr = idx >> 3, sub = idx & 7;
    const int b = sub >> 1, ih = sub & 1;
    const int h = pr - 6;
    unsigned short* obrow = xbf + ((size_t)b * 76 + pr) * 80 * 256;

    if ((unsigned)h >= 64u) {      // top/bottom pad rows: zero our ic-half
        const uint4 z = make_uint4(0, 0, 0, 0);
        for (int f = t; f < 80 * 16; f += 256) {
            const int col = f >> 4, k = f & 15;      // 16 uint4 per 128 shorts
            ((uint4*)obrow)[col * 32 + ih * 16 + k] = z;
        }
        return;
    }
    const float4* xr4 = (const float4*)(x + ((size_t)b * CIN + ih * 128) * 4096
                                        + (size_t)h * 64);
    #pragma unroll
    for (int i = 0; i < 2; ++i) {
        const int mt = t + i * 256;          // 512 microtiles: (w4 16) x (c4 32)
        const int w4 = mt & 15, c4 = mt >> 4;
        const float4 r0 = xr4[(size_t)(c4 * 4 + 0) * 1024 + w4];
        const float4 r1 = xr4[(size_t)(c4 * 4 + 1) * 1024 + w4];
        const float4 r2 = xr4[(size_t)(c4 * 4 + 2) * 1024 + w4];
        const float4 r3 = xr4[(size_t)(c4 * 4 + 3) * 1024 + w4];
        const float a0[4] = {r0.x, r0.y, r0.z, r0.w};
        const float a1[4] = {r1.x, r1.y, r1.z, r1.w};
        const float a2[4] = {r2.x, r2.y, r2.z, r2.w};
        const float a3[4] = {r3.x, r3.y, r3.z, r3.w};
        #pragma unroll
        for (int j = 0; j < 4; ++j) {
            const int w = w4 * 4 + j;
            lsq[w * 32 + (c4 ^ (w & 31))] =
                make_uint2(f2bf_pack(a0[j], a1[j]), f2bf_pack(a2[j], a3[j]));
        }
    }
    __syncthreads();
    uint2* oq = (uint2*)obrow;
    #pragma unroll
    for (int k = 0; k < 10; ++k) {           // 80 cols x 32 c4 / 256 threads
        const int f = t + k * 256;
        const int col = f >> 5, c4 = f & 31;
        const int w = col - 8;
        uint2 v = make_uint2(0, 0);
        if ((unsigned)w < 64u) v = lsq[w * 32 + (c4 ^ (w & 31))];
        oq[col * 64 + ih * 32 + c4] = v;
    }
}

// ---------------------------------------------------------------------------
// conv1 implicit GEMM, bf16 MFMA 16x16x32, KZ=8.  (r12/r13 version, verbatim)
// grid (32 hp, 8 kz, 4 b) = 1024 blocks; block 256 = 4 waves (64oc x 64px).
// Split-W pipelining: wbufA (taps 0-3) + wbufB (taps 4-6); stage WB(u) under
// taps 0-3, WA(u+1) under taps 4-6. LDS 77,824 B -> 2 blocks/CU.
// ---------------------------------------------------------------------------
__global__ __launch_bounds__(256) void conv1_mfma_kernel(
    const unsigned short* __restrict__ xbf, const unsigned short* __restrict__ w1t,
    unsigned short* __restrict__ P)
{
    __shared__ unsigned short wbufA[4 * 128 * 32];  // 32,768 B: taps u*7+{0..3}
    __shared__ unsigned short wbufB[3 * 128 * 32];  // 24,576 B: taps u*7+{4..6}
    __shared__ unsigned short xs[2][5120];          // 20,480 B: [row 2][col 80][ic32]

    const int hp = blockIdx.x, kz = blockIdx.y, b = blockIdx.z;
    const int h0 = hp * 2;
    const int t = threadIdx.x;               // 0..255
    const int lane = t & 63, wv = t >> 6;    // 4 waves
    const int oc_off = (wv & 1) * 64;
    const int ri = wv >> 1;                  // wave-uniform pixel row (0/1)
    const int l15 = lane & 15, quad = lane >> 4;
    const int wvbase = t & ~63;
    // quad-XOR swizzle term for wf reads ((oc_off+of*16)>>1 & 3 == 0)
    const int swf = (quad ^ ((l15 >> 1) & 3)) << 4;

    f32x4 acc[4][4];
    #pragma unroll
    for (int i = 0; i < 4; ++i)
        #pragma unroll
        for (int j = 0; j < 4; ++j) acc[i][j] = (f32x4){0.f, 0.f, 0.f, 0.f};

    const unsigned short* xrow =
        xbf + ((size_t)b * 76 + h0) * 80 * 256 + kz * 32;   // pr = h0 base

    // X tile: 640 16B chunks; chunk L: cell=L>>2 (row*80+col), qc=L&3.
    // source quad pre-swizzled: qs = qc ^ ((col>>1)&3); LDS dest linear.
#define STAGE_X(u_, bs_) do {                                                  \
    unsigned short* lb_ = &xs[bs_][0];                                         \
    _Pragma("unroll")                                                          \
    for (int i_ = 0; i_ < 3; ++i_) {                                           \
        if (i_ < 2 || t < 128) {        /* wave-uniform mask */                \
            const int L_ = i_ * 256 + t;                                       \
            const int cell_ = L_ >> 2, qc_ = L_ & 3;                           \
            const int row_ = (cell_ >= 80) ? 1 : 0;                           \
            const int col_ = cell_ - row_ * 80;                               \
            const int qs_ = qc_ ^ ((col_ >> 1) & 3);                           \
            const unsigned short* src_ =                                       \
                xrow + ((size_t)(2 * (u_) + row_) * 80 + col_) * 256 + qs_ * 8;\
            __builtin_amdgcn_global_load_lds(                                  \
                (const __attribute__((address_space(1))) unsigned int*)src_,   \
                (__attribute__((address_space(3))) unsigned int*)              \
                    (lb_ + ((size_t)i_ * 256 + wvbase) * 8),                   \
                16, 0, 0);                                                     \
        }                                                                      \
    }                                                                          \
} while (0)

    // WA: taps u*7+{0..3}: 2048 16B chunks, 8/thread. chunk c: tap=c>>9,
    // oc=(c>>2)&127, qc=c&3; source quad pre-swizzled (same XOR as reads).
#define STAGE_WA(u_) do {                                                      \
    const unsigned short* wsu_ = w1t + ((size_t)kz * 49 + (u_) * 7) * 4096;    \
    _Pragma("unroll")                                                          \
    for (int i_ = 0; i_ < 8; ++i_) {                                           \
        const int c_ = t + i_ * 256;                                           \
        const int tap_ = c_ >> 9, r_ = c_ & 511;                               \
        const int oc_ = r_ >> 2, qc_ = r_ & 3;                                 \
        const int qs_ = qc_ ^ ((oc_ >> 1) & 3);                                \
        const unsigned short* src_ =                                           \
            wsu_ + ((size_t)tap_ * 128 + oc_) * 32 + qs_ * 8;                  \
        __builtin_amdgcn_global_load_lds(                                      \
            (const __attribute__((address_space(1))) unsigned int*)src_,       \
            (__attribute__((address_space(3))) unsigned int*)                  \
                (wbufA + ((size_t)i_ * 256 + wvbase) * 8),                     \
            16, 0, 0);                                                         \
    }                                                                          \
} while (0)

    // WB: taps u*7+{4..6}: 1536 16B chunks, 6/thread.
#define STAGE_WB(u_) do {                                                      \
    const unsigned short* wsu_ = w1t + ((size_t)kz * 49 + (u_) * 7 + 4) * 4096;\
    _Pragma("unroll")                                                          \
    for (int i_ = 0; i_ < 6; ++i_) {                                           \
        const int c_ = t + i_ * 256;                                           \
        const int tap_ = c_ >> 9, r_ = c_ & 511;                               \
        const int oc_ = r_ >> 2, qc_ = r_ & 3;                                 \
        const int qs_ = qc_ ^ ((oc_ >> 1) & 3);                                \
        const unsigned short* src_ =                                           \
            wsu_ + ((size_t)tap_ * 128 + oc_) * 32 + qs_ * 8;                  \
        __builtin_amdgcn_global_load_lds(                                      \
            (const __attribute__((address_space(1))) unsigned int*)src_,       \
            (__attribute__((address_space(3))) unsigned int*)                  \
                (wbufB + ((size_t)i_ * 256 + wvbase) * 8),                     \
            16, 0, 0);                                                         \
    }                                                                          \
} while (0)

#define TAP(wt0_, v_, cb_) do {                                                \
    const char* wt_ = (const char*)(wt0_);                                     \
    bf16x8 wf0 = *(const bf16x8*)(wt_ + (oc_off      + l15) * 64 + swf);       \
    bf16x8 wf1 = *(const bf16x8*)(wt_ + (oc_off + 16 + l15) * 64 + swf);       \
    bf16x8 wf2 = *(const bf16x8*)(wt_ + (oc_off + 32 + l15) * 64 + swf);       \
    bf16x8 wf3 = *(const bf16x8*)(wt_ + (oc_off + 48 + l15) * 64 + swf);       \
    const int sc_ = l15 + 2 * (v_) + 2;                                        \
    const int sw_ = (quad ^ ((sc_ >> 1) & 3)) << 4;  /* same for all pf */     \
    bf16x8 xf0 = *(const bf16x8*)((cb_) + (ri * 80 + sc_     ) * 64 + sw_);    \
    bf16x8 xf1 = *(const bf16x8*)((cb_) + (ri * 80 + sc_ + 16) * 64 + sw_);    \
    bf16x8 xf2 = *(const bf16x8*)((cb_) + (ri * 80 + sc_ + 32) * 64 + sw_);    \
    bf16x8 xf3 = *(const bf16x8*)((cb_) + (ri * 80 + sc_ + 48) * 64 + sw_);    \
    acc[0][0] = __builtin_amdgcn_mfma_f32_16x16x32_bf16(wf0, xf0, acc[0][0], 0,0,0); \
    acc[0][1] = __builtin_amdgcn_mfma_f32_16x16x32_bf16(wf0, xf1, acc[0][1], 0,0,0); \
    acc[0][2] = __builtin_amdgcn_mfma_f32_16x16x32_bf16(wf0, xf2, acc[0][2], 0,0,0); \
    acc[0][3] = __builtin_amdgcn_mfma_f32_16x16x32_bf16(wf0, xf3, acc[0][3], 0,0,0); \
    acc[1][0] = __builtin_amdgcn_mfma_f32_16x16x32_bf16(wf1, xf0, acc[1][0], 0,0,0); \
    acc[1][1] = __builtin_amdgcn_mfma_f32_16x16x32_bf16(wf1, xf1, acc[1][1], 0,0,0); \
    acc[1][2] = __builtin_amdgcn_mfma_f32_16x16x32_bf16(wf1, xf2, acc[1][2], 0,0,0); \
    acc[1][3] = __builtin_amdgcn_mfma_f32_16x16x32_bf16(wf1, xf3, acc[1][3], 0,0,0); \
    acc[2][0] = __builtin_amdgcn_mfma_f32_16x16x32_bf16(wf2, xf0, acc[2][0], 0,0,0); \
    acc[2][1] = __builtin_amdgcn_mfma_f32_16x16x32_bf16(wf2, xf1, acc[2][1], 0,0,0); \
    acc[2][2] = __builtin_amdgcn_mfma_f32_16x16x32_bf16(wf2, xf2, acc[2][2], 0,0,0); \
    acc[2][3] = __builtin_amdgcn_mfma_f32_16x16x32_bf16(wf2, xf3, acc[2][3], 0,0,0); \
    acc[3][0] = __builtin_amdgcn_mfma_f32_16x16x32_bf16(wf3, xf0, acc[3][0], 0,0,0); \
    acc[3][1] = __builtin_amdgcn_mfma_f32_16x16x32_bf16(wf3, xf1, acc[3][1], 0,0,0); \
    acc[3][2] = __builtin_amdgcn_mfma_f32_16x16x32_bf16(wf3, xf2, acc[3][2], 0,0,0); \
    acc[3][3] = __builtin_amdgcn_mfma_f32_16x16x32_bf16(wf3, xf3, acc[3][3], 0,0,0); \
} while (0)

    // Section u: WB(u) staged under taps 0-3; WA(u+1) staged under taps 4-6.
#define USEC(u_, LAST_) do {                                                   \
    const char* cb_ = (const char*)&xs[(u_) & 1][0];                           \
    STAGE_WB(u_);                                                              \
    if (!(LAST_)) STAGE_X((u_) + 1, ((u_) + 1) & 1);                           \
    TAP(wbufA,             0, cb_);                                            \
    TAP(wbufA +  1 * 4096, 1, cb_);                                            \
    TAP(wbufA +  2 * 4096, 2, cb_);                                            \
    TAP(wbufA +  3 * 4096, 3, cb_);                                            \
    __syncthreads();                 /* WB+X landed; wbufA reads done */       \
    if (!(LAST_)) STAGE_WA((u_) + 1);                                          \
    TAP(wbufB,             4, cb_);                                            \
    TAP(wbufB +  1 * 4096, 5, cb_);                                            \
    TAP(wbufB +  2 * 4096, 6, cb_);                                            \
    if (!(LAST_)) __syncthreads();   /* WA(u+1) landed; wbufB reads done */    \
} while (0)

    STAGE_WA(0);
    STAGE_X(0, 0);
    __syncthreads();

    USEC(0, 0);
    USEC(1, 0);
    USEC(2, 0);
    USEC(3, 0);
    USEC(4, 0);
    USEC(5, 0);
    USEC(6, 1);

#undef STAGE_X
#undef STAGE_WA
#undef STAGE_WB
#undef TAP
#undef USEC

    unsigned short* Pb = P + (size_t)(kz * 4 + b) * (128 * 4096) + (size_t)(h0 + ri) * 64;
    #pragma unroll
    for (int of = 0; of < 4; ++of) {
        const int oc = oc_off + of * 16 + quad * 4;
        #pragma unroll
        for (int pf = 0; pf < 4; ++pf) {
            const int w = pf * 16 + l15;
            #pragma unroll
            for (int reg = 0; reg < 4; ++reg)
                Pb[(size_t)(oc + reg) * 4096 + w] = f2bf(acc[of][pf][reg]);
        }
    }
}

// ---------------------------------------------------------------------------
// FUSED conv2 (1x1, 128->49) + b2 + softmax + gather, W-SPLIT for TLP:
// grid (64 h, 4 b, 2 wh) = 512 blocks; block 512. Each block owns 32 of the
// 64 w-columns -- softmax is per-pixel so NOTHING is recomputed (unlike r9's
// pass-split). Per-block work halves, blocks/CU doubles (LDS 31,360 B,
// 2 blocks/CU = 4 waves/SIMD vs r13's 2). 2 channel passes of 128 each.
// ---------------------------------------------------------------------------
__global__ __launch_bounds__(512) void conv2_gather_kernel(
    const unsigned short* __restrict__ P, const float* __restrict__ w2,
    const float* __restrict__ b2, const float* __restrict__ b1,
    const float* __restrict__ x, float* __restrict__ out)
{
    __shared__ float k1s[32 * 140];   // 17,920 B
    __shared__ float k2s[32 * 56];    //  7,168 B
    __shared__ float as[NJ * 32];     //  6,272 B  (total 31,360)
    const int h = blockIdx.x, b = blockIdx.y, wh = blockIdx.z;
    const int wbase = wh * 32;
    const int t = threadIdx.x;

    // k1 = b1 + sum_kz P   (uint2 = 4 w per load); 1024 items / 512 thr
    #pragma unroll
    for (int it = 0; it < 2; ++it) {
        const int f = t + it * 512;
        const int wq = f & 7, oc = f >> 3;
        const float bv = b1[oc];
        float s0 = bv, s1 = bv, s2 = bv, s3 = bv;
        #pragma unroll
        for (int kzi = 0; kzi < KZ; ++kzi) {
            const uint2 u = *(const uint2*)
                &P[(((size_t)(kzi * 4 + b) * 128 + oc) * 64 + h) * 64
                   + wbase + 4 * wq];
            s0 += __uint_as_float(u.x << 16);
            s1 += __uint_as_float(u.x & 0xFFFF0000u);
            s2 += __uint_as_float(u.y << 16);
            s3 += __uint_as_float(u.y & 0xFFFF0000u);
        }
        k1s[(4 * wq + 0) * 140 + oc] = s0;
        k1s[(4 * wq + 1) * 140 + oc] = s1;
        k1s[(4 * wq + 2) * 140 + oc] = s2;
        k1s[(4 * wq + 3) * 140 + oc] = s3;
    }
    __syncthreads();

    const int w = t & 31, jg = t >> 5;       // jg 0..15 (7 active for conv2)
    float accj[7];
    if (jg < 7) {
        #pragma unroll
        for (int jj = 0; jj < 7; ++jj) accj[jj] = b2[7 * jg + jj];
        const float4* kv = (const float4*)&k1s[w * 140];
        for (int oc4 = 0; oc4 < 32; ++oc4) {
            float4 v = kv[oc4];
            #pragma unroll
            for (int jj = 0; jj < 7; ++jj) {
                const float* wr = w2 + (size_t)(7 * jg + jj) * OC1 + 4 * oc4;
                accj[jj] += v.x * wr[0] + v.y * wr[1] + v.z * wr[2] + v.w * wr[3];
            }
        }
        #pragma unroll
        for (int jj = 0; jj < 7; ++jj) k2s[w * 56 + 7 * jg + jj] = accj[jj];
    } else if (jg == 7) {
        #pragma unroll
        for (int j = 49; j < 56; ++j) k2s[w * 56 + j] = -1e30f;
    }
    __syncthreads();

    float4 vv[13];
    const float4* k2v = (const float4*)&k2s[w * 56];
    float m = -1e30f;
    #pragma unroll
    for (int i = 0; i < 13; ++i) {
        vv[i] = k2v[i];
        m = fmaxf(m, fmaxf(fmaxf(vv[i].x, vv[i].y), fmaxf(vv[i].z, vv[i].w)));
    }
    float s = 0.f;
    #pragma unroll
    for (int i = 0; i < 13; ++i) {
        s += __expf(vv[i].x - m) + __expf(vv[i].y - m)
           + __expf(vv[i].z - m) + __expf(vv[i].w - m);
    }
    const float inv = 1.f / s;
    if (jg < 7) {
        #pragma unroll
        for (int jj = 0; jj < 7; ++jj)
            as[(7 * jg + jj) * 32 + w] = __expf(accj[jj] - m) * inv;
    }
    __syncthreads();

    // gather: thread = (wp 8) x (cs 64); 2 passes cover 256 channels.
    const int wp = t & 7, cs = t >> 3;
    const int w0 = wp * 4;
    float* outb = out + (size_t)b * CIN * 4096 + (size_t)h * 64 + wbase + w0;

    #pragma unroll
    for (int pass = 0; pass < 2; ++pass) {
        const int c0 = pass * 128 + cs * 2;
        const float* xb = x + (size_t)(b * CIN + c0) * 4096;
        float ac[2][4];
        #pragma unroll
        for (int c = 0; c < 2; ++c)
            #pragma unroll
            for (int wi = 0; wi < 4; ++wi) ac[c][wi] = 0.f;

        #pragma unroll
        for (int u = 0; u < 7; ++u) {
            const int row = h + 2 * u - 6;
            if ((unsigned)row >= 64u) continue;
            float xr[2][20];
            #pragma unroll
            for (int c = 0; c < 2; ++c) {
                const float4* rp = (const float4*)(xb + (size_t)c * 4096 + row * 64);
                #pragma unroll
                for (int j = 0; j < 5; ++j) {
                    const int i4 = wh * 8 + wp - 2 + j;
                    float4 g = make_float4(0.f, 0.f, 0.f, 0.f);
                    if ((unsigned)i4 < 16u) g = rp[i4];
                    xr[c][4 * j + 0] = g.x; xr[c][4 * j + 1] = g.y;
                    xr[c][4 * j + 2] = g.z; xr[c][4 * j + 3] = g.w;
                }
            }
            #pragma unroll
            for (int v = 0; v < 7; ++v) {
                const float4 a4 = *(const float4*)&as[(u * 7 + v) * 32 + w0];
                const float av[4] = {a4.x, a4.y, a4.z, a4.w};
                #pragma unroll
                for (int wi = 0; wi < 4; ++wi)
                    #pragma unroll
                    for (int c = 0; c < 2; ++c)
                        ac[c][wi] += av[wi] * xr[c][wi + 2 * v + 2];
            }
        }
        #pragma unroll
        for (int c = 0; c < 2; ++c) {
            float4 st = make_float4(ac[c][0], ac[c][1], ac[c][2], ac[c][3]);
            *(float4*)&outb[(size_t)(c0 + c) * 4096] = st;
        }
    }
}

// ---------------------------------------------------------------------------
// ws layout:
//   w1t bf16 [8][49][128][32]            3,211,264 B
//   xbf bf16 [4][76][80][256]           12,451,840 B
//   P   bf16 [8][4][128][4096]          33,554,432 B   (total ~49.2 MB)
// ---------------------------------------------------------------------------
extern "C" void kernel_launch(void* const* d_in, const int* in_sizes, int n_in,
                              void* d_out, int out_size, void* d_ws, size_t ws_size,
                              hipStream_t stream) {
    const float* x  = (const float*)d_in[0];
    const float* w1 = (const float*)d_in[1];
    const float* b1 = (const float*)d_in[2];
    const float* w2 = (const float*)d_in[3];
    const float* b2 = (const float*)d_in[4];
    float* out = (float*)d_out;

    unsigned short* w1t = (unsigned short*)d_ws;
    unsigned short* xbf = (unsigned short*)((char*)d_ws + 3211264);
    unsigned short* P   = (unsigned short*)((char*)d_ws + 3211264 + 12451840);

    prep_kernel<<<864, 256, 0, stream>>>(w1, w1t, x, xbf);
    conv1_mfma_kernel<<<dim3(32, KZ, 4), 256, 0, stream>>>(xbf, w1t, P);
    conv2_gather_kernel<<<dim3(HW, 4, 2), 512, 0, stream>>>(P, w2, b2, b1, x, out);
}

// Round 15
// 166.753 us; speedup vs baseline: 1.0384x; 1.0384x over previous
//
#include <hip/hip_runtime.h>

#define HW 64
#define CIN 256
#define OC1 128
#define NJ 49
#define KZQ 4                // conv1 K-split: 4 block-slices x 64 ic (2x32 in-reg)

typedef short bf16x8 __attribute__((ext_vector_type(8)));
typedef float f32x4 __attribute__((ext_vector_type(4)));

__device__ __forceinline__ unsigned f2bf_pack(float a, float b) {
    unsigned ua = __float_as_uint(a);
    ua += 0x7FFF + ((ua >> 16) & 1);
    unsigned ub = __float_as_uint(b);
    ub += 0x7FFF + ((ub >> 16) & 1);
    return (ua >> 16) | (ub & 0xFFFF0000u);
}

__device__ __forceinline__ unsigned short f2bf(float a) {
    unsigned u = __float_as_uint(a);
    u += 0x7FFF + ((u >> 16) & 1);
    return (unsigned short)(u >> 16);
}

// ---------------------------------------------------------------------------
// prep: merged wtrans + xtrans (one launch, tails overlap).   (r13 verbatim)
// blocks 0..255:   w1 fp32 [128][256][49] -> w1t bf16 [kz8][tap49][oc128][ic32]
// blocks 256..863: x fp32 [b][256][64][64] -> xbf bf16 [b][76pr][80col][256ic]
// ---------------------------------------------------------------------------
__global__ __launch_bounds__(256) void prep_kernel(
    const float* __restrict__ w1, unsigned short* __restrict__ w1t,
    const float* __restrict__ x, unsigned short* __restrict__ xbf)
{
    __shared__ __align__(16) char smraw[25088];
    const int t = threadIdx.x;

    if (blockIdx.x < 256) {
        // ---- wtrans ----
        float* ws = (float*)smraw;            // [ic-local 128][tap 49]
        const int oc = blockIdx.x >> 1, ih = blockIdx.x & 1;
        const float4* src = (const float4*)(w1 + ((size_t)oc * 256 + ih * 128) * 49);
        for (int f = t; f < 1568; f += 256)
            ((float4*)ws)[f] = src[f];
        __syncthreads();
        for (int f = t; f < 4 * 49 * 32; f += 256) {
            const int icl = f & 31, r = f >> 5;          // r = kzl*49 + tap
            const int kzl = r / 49, tap = r - kzl * 49;
            // LDS read stride 49 words (odd) -> conflict-free
            w1t[(((size_t)(ih * 4 + kzl) * 49 + tap) * 128 + oc) * 32 + icl] =
                f2bf(ws[(kzl * 32 + icl) * 49 + tap]);
        }
        return;
    }

    // ---- xtrans ----
    uint2* lsq = (uint2*)smraw;               // [w][c4], c4 XOR-swizzled by w
    const int idx = blockIdx.x - 256;         // 608 = 76 * 8
    const int pr = idx >> 3, sub = idx & 7;
    const int b = sub >> 1, ih = sub & 1;
    const int h = pr - 6;
    unsigned short* obrow = xbf + ((size_t)b * 76 + pr) * 80 * 256;

    if ((unsigned)h >= 64u) {      // top/bottom pad rows: zero our ic-half
        const uint4 z = make_uint4(0, 0, 0, 0);
        for (int f = t; f < 80 * 16; f += 256) {
            const int col = f >> 4, k = f & 15;      // 16 uint4 per 128 shorts
            ((uint4*)obrow)[col * 32 + ih * 16 + k] = z;
        }
        return;
    }
    const float4* xr4 = (const float4*)(x + ((size_t)b * CIN + ih * 128) * 4096
                                        + (size_t)h * 64);
    #pragma unroll
    for (int i = 0; i < 2; ++i) {
        const int mt = t + i * 256;          // 512 microtiles: (w4 16) x (c4 32)
        const int w4 = mt & 15, c4 = mt >> 4;
        const float4 r0 = xr4[(size_t)(c4 * 4 + 0) * 1024 + w4];
        const float4 r1 = xr4[(size_t)(c4 * 4 + 1) * 1024 + w4];
        const float4 r2 = xr4[(size_t)(c4 * 4 + 2) * 1024 + w4];
        const float4 r3 = xr4[(size_t)(c4 * 4 + 3) * 1024 + w4];
        const float a0[4] = {r0.x, r0.y, r0.z, r0.w};
        const float a1[4] = {r1.x, r1.y, r1.z, r1.w};
        const float a2[4] = {r2.x, r2.y, r2.z, r2.w};
        const float a3[4] = {r3.x, r3.y, r3.z, r3.w};
        #pragma unroll
        for (int j = 0; j < 4; ++j) {
            const int w = w4 * 4 + j;
            lsq[w * 32 + (c4 ^ (w & 31))] =
                make_uint2(f2bf_pack(a0[j], a1[j]), f2bf_pack(a2[j], a3[j]));
        }
    }
    __syncthreads();
    uint2* oq = (uint2*)obrow;
    #pragma unroll
    for (int k = 0; k < 10; ++k) {           // 80 cols x 32 c4 / 256 threads
        const int f = t + k * 256;
        const int col = f >> 5, c4 = f & 31;
        const int w = col - 8;
        uint2 v = make_uint2(0, 0);
        if ((unsigned)w < 64u) v = lsq[w * 32 + (c4 ^ (w & 31))];
        oq[col * 64 + ih * 32 + c4] = v;
    }
}

// ---------------------------------------------------------------------------
// conv1 implicit GEMM, bf16 MFMA 16x16x32.
// grid (32 hp, 4 kzq, 4 b) = 512 blocks = EXACTLY 2/CU, one dispatch round
// (r13's 1024 blocks ran 2 rounds -> 2 pipeline fills/drains).
// Each block accumulates TWO 32-ic slices (kz = 2*kzq + kzh) in-register:
// the r12 split-W 7-section ladder runs twice under `#pragma unroll 1`
// (no code duplication), acc carries across; one extra barrier per block.
// P shrinks 33.5 -> 16.8 MB. LDS 77,824 B -> 2 blocks/CU, same swizzles.
// ---------------------------------------------------------------------------
__global__ __launch_bounds__(256) void conv1_mfma_kernel(
    const unsigned short* __restrict__ xbf, const unsigned short* __restrict__ w1t,
    unsigned short* __restrict__ P)
{
    __shared__ unsigned short wbufA[4 * 128 * 32];  // 32,768 B: taps u*7+{0..3}
    __shared__ unsigned short wbufB[3 * 128 * 32];  // 24,576 B: taps u*7+{4..6}
    __shared__ unsigned short xs[2][5120];          // 20,480 B: [row 2][col 80][ic32]

    const int hp = blockIdx.x, kzq = blockIdx.y, b = blockIdx.z;
    const int h0 = hp * 2;
    const int t = threadIdx.x;               // 0..255
    const int lane = t & 63, wv = t >> 6;    // 4 waves
    const int oc_off = (wv & 1) * 64;
    const int ri = wv >> 1;                  // wave-uniform pixel row (0/1)
    const int l15 = lane & 15, quad = lane >> 4;
    const int wvbase = t & ~63;
    // quad-XOR swizzle term for wf reads ((oc_off+of*16)>>1 & 3 == 0)
    const int swf = (quad ^ ((l15 >> 1) & 3)) << 4;

    f32x4 acc[4][4];
    #pragma unroll
    for (int i = 0; i < 4; ++i)
        #pragma unroll
        for (int j = 0; j < 4; ++j) acc[i][j] = (f32x4){0.f, 0.f, 0.f, 0.f};

    const unsigned short* wkz;   // per-kz bases (runtime, set in kzh loop)
    const unsigned short* xkz;

    // X tile: 640 16B chunks; chunk L: cell=L>>2 (row*80+col), qc=L&3.
    // source quad pre-swizzled: qs = qc ^ ((col>>1)&3); LDS dest linear.
#define STAGE_X(u_, bs_) do {                                                  \
    unsigned short* lb_ = &xs[bs_][0];                                         \
    _Pragma("unroll")                                                          \
    for (int i_ = 0; i_ < 3; ++i_) {                                           \
        if (i_ < 2 || t < 128) {        /* wave-uniform mask */                \
            const int L_ = i_ * 256 + t;                                       \
            const int cell_ = L_ >> 2, qc_ = L_ & 3;                           \
            const int row_ = (cell_ >= 80) ? 1 : 0;                           \
            const int col_ = cell_ - row_ * 80;                               \
            const int qs_ = qc_ ^ ((col_ >> 1) & 3);                           \
            const unsigned short* src_ =                                       \
                xkz + ((size_t)(2 * (u_) + row_) * 80 + col_) * 256 + qs_ * 8; \
            __builtin_amdgcn_global_load_lds(                                  \
                (const __attribute__((address_space(1))) unsigned int*)src_,   \
                (__attribute__((address_space(3))) unsigned int*)              \
                    (lb_ + ((size_t)i_ * 256 + wvbase) * 8),                   \
                16, 0, 0);                                                     \
        }                                                                      \
    }                                                                          \
} while (0)

    // WA: taps u*7+{0..3}: 2048 16B chunks, 8/thread. chunk c: tap=c>>9,
    // oc=(c>>2)&127, qc=c&3; source quad pre-swizzled (same XOR as reads).
#define STAGE_WA(u_) do {                                                      \
    const unsigned short* wsu_ = wkz + (size_t)(u_) * 7 * 4096;                \
    _Pragma("unroll")                                                          \
    for (int i_ = 0; i_ < 8; ++i_) {                                           \
        const int c_ = t + i_ * 256;                                           \
        const int tap_ = c_ >> 9, r_ = c_ & 511;                               \
        const int oc_ = r_ >> 2, qc_ = r_ & 3;                                 \
        const int qs_ = qc_ ^ ((oc_ >> 1) & 3);                                \
        const unsigned short* src_ =                                           \
            wsu_ + ((size_t)tap_ * 128 + oc_) * 32 + qs_ * 8;                  \
        __builtin_amdgcn_global_load_lds(                                      \
            (const __attribute__((address_space(1))) unsigned int*)src_,       \
            (__attribute__((address_space(3))) unsigned int*)                  \
                (wbufA + ((size_t)i_ * 256 + wvbase) * 8),                     \
            16, 0, 0);                                                         \
    }                                                                          \
} while (0)

    // WB: taps u*7+{4..6}: 1536 16B chunks, 6/thread.
#define STAGE_WB(u_) do {                                                      \
    const unsigned short* wsu_ = wkz + ((size_t)(u_) * 7 + 4) * 4096;          \
    _Pragma("unroll")                                                          \
    for (int i_ = 0; i_ < 6; ++i_) {                                           \
        const int c_ = t + i_ * 256;                                           \
        const int tap_ = c_ >> 9, r_ = c_ & 511;                               \
        const int oc_ = r_ >> 2, qc_ = r_ & 3;                                 \
        const int qs_ = qc_ ^ ((oc_ >> 1) & 3);                                \
        const unsigned short* src_ =                                           \
            wsu_ + ((size_t)tap_ * 128 + oc_) * 32 + qs_ * 8;                  \
        __builtin_amdgcn_global_load_lds(                                      \
            (const __attribute__((address_space(1))) unsigned int*)src_,       \
            (__attribute__((address_space(3))) unsigned int*)                  \
                (wbufB + ((size_t)i_ * 256 + wvbase) * 8),                     \
            16, 0, 0);                                                         \
    }                                                                          \
} while (0)

#define TAP(wt0_, v_, cb_) do {                                                \
    const char* wt_ = (const char*)(wt0_);                                     \
    bf16x8 wf0 = *(const bf16x8*)(wt_ + (oc_off      + l15) * 64 + swf);       \
    bf16x8 wf1 = *(const bf16x8*)(wt_ + (oc_off + 16 + l15) * 64 + swf);       \
    bf16x8 wf2 = *(const bf16x8*)(wt_ + (oc_off + 32 + l15) * 64 + swf);       \
    bf16x8 wf3 = *(const bf16x8*)(wt_ + (oc_off + 48 + l15) * 64 + swf);       \
    const int sc_ = l15 + 2 * (v_) + 2;                                        \
    const int sw_ = (quad ^ ((sc_ >> 1) & 3)) << 4;  /* same for all pf */     \
    bf16x8 xf0 = *(const bf16x8*)((cb_) + (ri * 80 + sc_     ) * 64 + sw_);    \
    bf16x8 xf1 = *(const bf16x8*)((cb_) + (ri * 80 + sc_ + 16) * 64 + sw_);    \
    bf16x8 xf2 = *(const bf16x8*)((cb_) + (ri * 80 + sc_ + 32) * 64 + sw_);    \
    bf16x8 xf3 = *(const bf16x8*)((cb_) + (ri * 80 + sc_ + 48) * 64 + sw_);    \
    acc[0][0] = __builtin_amdgcn_mfma_f32_16x16x32_bf16(wf0, xf0, acc[0][0], 0,0,0); \
    acc[0][1] = __builtin_amdgcn_mfma_f32_16x16x32_bf16(wf0, xf1, acc[0][1], 0,0,0); \
    acc[0][2] = __builtin_amdgcn_mfma_f32_16x16x32_bf16(wf0, xf2, acc[0][2], 0,0,0); \
    acc[0][3] = __builtin_amdgcn_mfma_f32_16x16x32_bf16(wf0, xf3, acc[0][3], 0,0,0); \
    acc[1][0] = __builtin_amdgcn_mfma_f32_16x16x32_bf16(wf1, xf0, acc[1][0], 0,0,0); \
    acc[1][1] = __builtin_amdgcn_mfma_f32_16x16x32_bf16(wf1, xf1, acc[1][1], 0,0,0); \
    acc[1][2] = __builtin_amdgcn_mfma_f32_16x16x32_bf16(wf1, xf2, acc[1][2], 0,0,0); \
    acc[1][3] = __builtin_amdgcn_mfma_f32_16x16x32_bf16(wf1, xf3, acc[1][3], 0,0,0); \
    acc[2][0] = __builtin_amdgcn_mfma_f32_16x16x32_bf16(wf2, xf0, acc[2][0], 0,0,0); \
    acc[2][1] = __builtin_amdgcn_mfma_f32_16x16x32_bf16(wf2, xf1, acc[2][1], 0,0,0); \
    acc[2][2] = __builtin_amdgcn_mfma_f32_16x16x32_bf16(wf2, xf2, acc[2][2], 0,0,0); \
    acc[2][3] = __builtin_amdgcn_mfma_f32_16x16x32_bf16(wf2, xf3, acc[2][3], 0,0,0); \
    acc[3][0] = __builtin_amdgcn_mfma_f32_16x16x32_bf16(wf3, xf0, acc[3][0], 0,0,0); \
    acc[3][1] = __builtin_amdgcn_mfma_f32_16x16x32_bf16(wf3, xf1, acc[3][1], 0,0,0); \
    acc[3][2] = __builtin_amdgcn_mfma_f32_16x16x32_bf16(wf3, xf2, acc[3][2], 0,0,0); \
    acc[3][3] = __builtin_amdgcn_mfma_f32_16x16x32_bf16(wf3, xf3, acc[3][3], 0,0,0); \
} while (0)

    // Section u: WB(u) staged under taps 0-3; WA(u+1) staged under taps 4-6.
#define USEC(u_, LAST_) do {                                                   \
    const char* cb_ = (const char*)&xs[(u_) & 1][0];                           \
    STAGE_WB(u_);                                                              \
    if (!(LAST_)) STAGE_X((u_) + 1, ((u_) + 1) & 1);                           \
    TAP(wbufA,             0, cb_);                                            \
    TAP(wbufA +  1 * 4096, 1, cb_);                                            \
    TAP(wbufA +  2 * 4096, 2, cb_);                                            \
    TAP(wbufA +  3 * 4096, 3, cb_);                                            \
    __syncthreads();                 /* WB+X landed; wbufA reads done */       \
    if (!(LAST_)) STAGE_WA((u_) + 1);                                          \
    TAP(wbufB,             4, cb_);                                            \
    TAP(wbufB +  1 * 4096, 5, cb_);                                            \
    TAP(wbufB +  2 * 4096, 6, cb_);                                            \
    if (!(LAST_)) __syncthreads();   /* WA(u+1) landed; wbufB reads done */    \
} while (0)

    #pragma unroll 1
    for (int kzh = 0; kzh < 2; ++kzh) {
        const int kz = kzq * 2 + kzh;                    // 32-ic slice index
        wkz = w1t + (size_t)kz * 49 * 4096;
        xkz = xbf + ((size_t)b * 76 + h0) * 80 * 256 + kz * 32;
        if (kzh) __syncthreads();        // prev half's wbufB/xs reads done
        STAGE_WA(0);
        STAGE_X(0, 0);
        __syncthreads();
        USEC(0, 0);
        USEC(1, 0);
        USEC(2, 0);
        USEC(3, 0);
        USEC(4, 0);
        USEC(5, 0);
        USEC(6, 1);
    }

#undef STAGE_X
#undef STAGE_WA
#undef STAGE_WB
#undef TAP
#undef USEC

    unsigned short* Pb = P + (size_t)(kzq * 4 + b) * (128 * 4096) + (size_t)(h0 + ri) * 64;
    #pragma unroll
    for (int of = 0; of < 4; ++of) {
        const int oc = oc_off + of * 16 + quad * 4;
        #pragma unroll
        for (int pf = 0; pf < 4; ++pf) {
            const int w = pf * 16 + l15;
            #pragma unroll
            for (int reg = 0; reg < 4; ++reg)
                Pb[(size_t)(oc + reg) * 4096 + w] = f2bf(acc[of][pf][reg]);
        }
    }
}

// ---------------------------------------------------------------------------
// FUSED conv2 (1x1, 128->49) + b2 + softmax + gather.  (r13 structure; KZQ=4)
// grid (64 h, 4 b) = 256 blocks; block 512. Softmax once per (h,b); 4 channel
// passes in-block. P read halves vs r13 (16.8 MB), k1 loop 8 -> 4 rounds.
// LDS 62,720 B -> 2 blocks/CU... (1 block/CU at 62.7KB; unchanged from r13).
// ---------------------------------------------------------------------------
__global__ __launch_bounds__(512, 2) void conv2_gather_kernel(
    const unsigned short* __restrict__ P, const float* __restrict__ w2,
    const float* __restrict__ b2, const float* __restrict__ b1,
    const float* __restrict__ x, float* __restrict__ out)
{
    __shared__ float k1s[64 * 140];   // 35,840 B
    __shared__ float k2s[64 * 56];    // 14,336 B
    __shared__ float as[NJ * 64];     // 12,544 B  (total 62,720 <= 64K)
    const int h = blockIdx.x, b = blockIdx.y;
    const int t = threadIdx.x;

    for (int f = t; f < OC1 * 16; f += 512) {        // (oc, 4-w group) pairs
        const int wq = f & 15, oc = f >> 4;
        const float bv = b1[oc];
        float s0 = bv, s1 = bv, s2 = bv, s3 = bv;
        #pragma unroll
        for (int kzi = 0; kzi < KZQ; ++kzi) {
            const uint2 u = *(const uint2*)
                &P[(((size_t)(kzi * 4 + b) * 128 + oc) * 64 + h) * 64 + 4 * wq];
            s0 += __uint_as_float(u.x << 16);
            s1 += __uint_as_float(u.x & 0xFFFF0000u);
            s2 += __uint_as_float(u.y << 16);
            s3 += __uint_as_float(u.y & 0xFFFF0000u);
        }
        k1s[(4 * wq + 0) * 140 + oc] = s0;
        k1s[(4 * wq + 1) * 140 + oc] = s1;
        k1s[(4 * wq + 2) * 140 + oc] = s2;
        k1s[(4 * wq + 3) * 140 + oc] = s3;
    }
    __syncthreads();

    const int w = t & 63, jg = t >> 6;
    float accj[7];
    if (jg < 7) {
        #pragma unroll
        for (int jj = 0; jj < 7; ++jj) accj[jj] = b2[7 * jg + jj];
        const float4* kv = (const float4*)&k1s[w * 140];
        for (int oc4 = 0; oc4 < 32; ++oc4) {
            float4 v = kv[oc4];
            #pragma unroll
            for (int jj = 0; jj < 7; ++jj) {
                const float* wr = w2 + (size_t)(7 * jg + jj) * OC1 + 4 * oc4;
                accj[jj] += v.x * wr[0] + v.y * wr[1] + v.z * wr[2] + v.w * wr[3];
            }
        }
        #pragma unroll
        for (int jj = 0; jj < 7; ++jj) k2s[w * 56 + 7 * jg + jj] = accj[jj];
    } else {
        #pragma unroll
        for (int j = 49; j < 56; ++j) k2s[w * 56 + j] = -1e30f;
    }
    __syncthreads();

    float4 vv[13];
    const float4* k2v = (const float4*)&k2s[w * 56];
    float m = -1e30f;
    #pragma unroll
    for (int i = 0; i < 13; ++i) {
        vv[i] = k2v[i];
        m = fmaxf(m, fmaxf(fmaxf(vv[i].x, vv[i].y), fmaxf(vv[i].z, vv[i].w)));
    }
    float s = 0.f;
    #pragma unroll
    for (int i = 0; i < 13; ++i) {
        s += __expf(vv[i].x - m) + __expf(vv[i].y - m)
           + __expf(vv[i].z - m) + __expf(vv[i].w - m);
    }
    const float inv = 1.f / s;
    if (jg < 7) {
        #pragma unroll
        for (int jj = 0; jj < 7; ++jj)
            as[(7 * jg + jj) * 64 + w] = __expf(accj[jj] - m) * inv;
    }
    __syncthreads();

    // gather: thread = (wp 16) x (cs 32); 4 passes cover 256 channels.
    const int wp = t & 15, cs = t >> 4;
    const int w0 = wp * 4;
    float* outb = out + (size_t)b * CIN * 4096 + (size_t)h * 64 + w0;

    for (int pass = 0; pass < 4; ++pass) {
        const int c0 = pass * 64 + cs * 2;
        const float* xb = x + (size_t)(b * CIN + c0) * 4096;
        float ac[2][4];
        #pragma unroll
        for (int c = 0; c < 2; ++c)
            #pragma unroll
            for (int wi = 0; wi < 4; ++wi) ac[c][wi] = 0.f;

        #pragma unroll
        for (int u = 0; u < 7; ++u) {
            const int row = h + 2 * u - 6;
            if ((unsigned)row >= 64u) continue;
            float xr[2][20];
            #pragma unroll
            for (int c = 0; c < 2; ++c) {
                const float4* rp = (const float4*)(xb + (size_t)c * 4096 + row * 64);
                #pragma unroll
                for (int j = 0; j < 5; ++j) {
                    const int i4 = wp - 2 + j;
                    float4 g = make_float4(0.f, 0.f, 0.f, 0.f);
                    if ((unsigned)i4 < 16u) g = rp[i4];
                    xr[c][4 * j + 0] = g.x; xr[c][4 * j + 1] = g.y;
                    xr[c][4 * j + 2] = g.z; xr[c][4 * j + 3] = g.w;
                }
            }
            #pragma unroll
            for (int v = 0; v < 7; ++v) {
                const float4 a4 = *(const float4*)&as[(u * 7 + v) * 64 + w0];
                const float av[4] = {a4.x, a4.y, a4.z, a4.w};
                #pragma unroll
                for (int wi = 0; wi < 4; ++wi)
                    #pragma unroll
                    for (int c = 0; c < 2; ++c)
                        ac[c][wi] += av[wi] * xr[c][wi + 2 * v + 2];
            }
        }
        #pragma unroll
        for (int c = 0; c < 2; ++c) {
            float4 st = make_float4(ac[c][0], ac[c][1], ac[c][2], ac[c][3]);
            *(float4*)&outb[(size_t)(c0 + c) * 4096] = st;
        }
    }
}

// ---------------------------------------------------------------------------
// ws layout:
//   w1t bf16 [8][49][128][32]            3,211,264 B
//   xbf bf16 [4][76][80][256]           12,451,840 B
//   P   bf16 [4][4][128][4096]          16,777,216 B   (total ~32.4 MB)
// ---------------------------------------------------------------------------
extern "C" void kernel_launch(void* const* d_in, const int* in_sizes, int n_in,
                              void* d_out, int out_size, void* d_ws, size_t ws_size,
                              hipStream_t stream) {
    const float* x  = (const float*)d_in[0];
    const float* w1 = (const float*)d_in[1];
    const float* b1 = (const float*)d_in[2];
    const float* w2 = (const float*)d_in[3];
    const float* b2 = (const float*)d_in[4];
    float* out = (float*)d_out;

    unsigned short* w1t = (unsigned short*)d_ws;
    unsigned short* xbf = (unsigned short*)((char*)d_ws + 3211264);
    unsigned short* P   = (unsigned short*)((char*)d_ws + 3211264 + 12451840);

    prep_kernel<<<864, 256, 0, stream>>>(w1, w1t, x, xbf);
    conv1_mfma_kernel<<<dim3(32, KZQ, 4), 256, 0, stream>>>(xbf, w1t, P);
    conv2_gather_kernel<<<dim3(HW, 4), 512, 0, stream>>>(P, w2, b2, b1, x, out);
}